// Round 19
// baseline (192.204 us; speedup 1.0000x reference)
//
#include <hip/hip_runtime.h>
#include <hip/hip_bf16.h>
#include <math.h>

#define BB 8
#define CH 64
#define NP 4096
#define RG 32
#define R3 32768
#define LEAK 0.2f
#define BNEPS 1e-5f
#define GNEPS 1e-5f
#define SS3 602   // LDS cb-region stride (16B units) for 600-cell halo; %8==2

typedef short short8 __attribute__((ext_vector_type(8)));
typedef float float4_ __attribute__((ext_vector_type(4)));

__device__ __forceinline__ short f2bf(float f){
  unsigned u = __float_as_uint(f);
  u += 0x7FFF + ((u>>16)&1);          // RNE
  return (short)(u>>16);
}
__device__ __forceinline__ float bf2f(short s){
  unsigned u = ((unsigned)(unsigned short)s)<<16;
  return __uint_as_float(u);
}

// ---------------- voxelize stats ----------------
__global__ void k_voxstats(const float* __restrict__ coords, float* __restrict__ ms){
  int b = blockIdx.x;
  __shared__ float red[256];
  float mean[3];
  for(int d=0; d<3; d++){
    float s=0.f;
    for(int i=threadIdx.x; i<NP; i+=256) s += coords[(b*3+d)*NP+i];
    red[threadIdx.x]=s; __syncthreads();
    for(int o=128;o>0;o>>=1){ if(threadIdx.x<o) red[threadIdx.x]+=red[threadIdx.x+o]; __syncthreads(); }
    mean[d]=red[0]/(float)NP; __syncthreads();
  }
  float mx=0.f;
  for(int i=threadIdx.x; i<NP; i+=256){
    float x=coords[(b*3+0)*NP+i]-mean[0];
    float y=coords[(b*3+1)*NP+i]-mean[1];
    float z=coords[(b*3+2)*NP+i]-mean[2];
    mx=fmaxf(mx, sqrtf(x*x+y*y+z*z));
  }
  red[threadIdx.x]=mx; __syncthreads();
  for(int o=128;o>0;o>>=1){ if(threadIdx.x<o) red[threadIdx.x]=fmaxf(red[threadIdx.x],red[threadIdx.x+o]); __syncthreads(); }
  if(threadIdx.x==0){
    ms[b*4+0]=mean[0]; ms[b*4+1]=mean[1]; ms[b*4+2]=mean[2];
    ms[b*4+3]=red[0]*2.0f;
  }
}

// ------- fused: norm coords + voxel index + zero touched voxels -------
__global__ void k_assignzero(const float* __restrict__ coords, const float* __restrict__ ms,
                             float* __restrict__ nc, int* __restrict__ vi,
                             float* __restrict__ gsum){
  int wid = (blockIdx.x*256+threadIdx.x)>>6;
  int lane = threadIdx.x&63;
  if(wid>=BB*NP) return;
  int b=wid>>12, n=wid&4095;
  float scale=ms[b*4+3];
  float v[3]; int vox[3];
  #pragma unroll
  for(int d=0; d<3; d++){
    float c=coords[(b*3+d)*NP+n] - ms[b*4+d];
    float vv=(c/scale + 0.5f)*32.0f;
    vv=fminf(fmaxf(vv,0.0f),31.0f);
    v[d]=vv;
    vox[d]=(int)rintf(vv);
  }
  int idx=vox[0]*1024+vox[1]*32+vox[2];
  if(lane<3) nc[(b*3+lane)*NP+n]=v[lane];
  if(lane==0) vi[wid]=idx;
  gsum[((size_t)b*R3+idx)*CH + lane]=0.f;
}

// --------- scatter: LDS-transposed feat tile, wave-per-point atomics ----------
__global__ __launch_bounds__(256,2) void k_scatter(
    const float* __restrict__ feat, const int* __restrict__ vi,
    float* __restrict__ gsum, float* __restrict__ cnt){
  __shared__ float ft[64][65];
  int tid=threadIdx.x;
  int blk=blockIdx.x;                 // 512: b(8) x 64 point-chunks
  int b=blk>>6, n0=(blk&63)*64;
  for(int e=tid;e<4096;e+=256){
    int c=e>>6, nl=e&63;
    ft[nl][c]=feat[(size_t)(b*CH+c)*NP + n0+nl];
  }
  __syncthreads();
  int lane=tid&63, wv=tid>>6;
  for(int p=wv;p<64;p+=4){
    int idx=vi[(b<<12)+n0+p];
    atomicAdd(gsum + ((size_t)b*R3+idx)*CH + lane, ft[p][lane]);
    if(lane==0) atomicAdd(&cnt[b*R3+idx], 1.0f);
  }
}

// ------- sums -> means, cnt-guarded -------
__global__ void k_gridmean(const float* __restrict__ gsum, const float* __restrict__ cnt,
                           short* __restrict__ gbf){
  int t=blockIdx.x*256+threadIdx.x;
  if(t>=BB*R3*8) return;
  int v=t>>3, q=t&7;
  float c=cnt[v];
  short8 o={0,0,0,0,0,0,0,0};
  if(c!=0.f){
    float inv=1.0f/c;
    const float* sp=gsum + (size_t)v*CH + q*8;
    #pragma unroll
    for(int j=0;j<8;j++) o[j]=f2bf(sp[j]*inv);
  }
  ((short8*)gbf)[(size_t)v*8+q]=o;
}

// ------- both conv weights -> per-fragment contiguous bf16 -------
__global__ void k_wt3x2(const float* __restrict__ wa, const float* __restrict__ wb,
                        short* __restrict__ oa, short* __restrict__ ob){
  int t=blockIdx.x*256+threadIdx.x;
  if(t>=2*CH*CH*27) return;
  const float* w = (t<CH*CH*27)? wa : wb;
  short* o = (t<CH*CH*27)? oa : ob;
  int tt = (t<CH*CH*27)? t : t-CH*CH*27;
  int frag=tt>>9, l=(tt>>3)&63, j=tt&7;
  int tap=frag>>3, hh=(frag>>2)&1, nf=frag&3;
  int oc=nf*16+(l&15);
  int ci=hh*32+(l>>4)*8+j;
  o[tt]=f2bf(w[oc*1728 + ci*27 + tap]);
}

// ------------- MFMA implicit-GEMM 3x3x3 conv + bias + BN + leaky -------------
// tile 4z x 8y x 8x (256 cells), 4 waves (wave = z-layer, M=64 cells/wave).
// ALL 64 ci staged once: 77 KB DYNAMIC LDS -> 2 blocks/CU.
// T5: s_setprio(1) around each tap's 32-MFMA cluster (co-resident block is
// staging while this one computes -> scheduler role diversity).
#define CONV_TAP(AF, BW) \
  __builtin_amdgcn_s_setprio(1); \
  _Pragma("unroll") for(int ks=0;ks<2;ks++) \
    _Pragma("unroll") for(int mf=0;mf<4;mf++) \
      _Pragma("unroll") for(int nf=0;nf<4;nf++) \
        acc[mf][nf]=__builtin_amdgcn_mfma_f32_16x16x32_bf16(AF[ks*4+mf],BW[ks*4+nf],acc[mf][nf],0,0,0); \
  __builtin_amdgcn_s_setprio(0);

__global__ __launch_bounds__(256,2) void k_conv_mfma(
    const short* __restrict__ gin, short* __restrict__ gout,
    const short* __restrict__ wt3, const float* __restrict__ bias,
    const float* __restrict__ bg, const float* __restrict__ bb,
    const float* __restrict__ bm, const float* __restrict__ bv){
  extern __shared__ __align__(16) short in_s[];   // 8*SS3*8 shorts = 77056 B
  int tid=threadIdx.x;
  int bid=blockIdx.x;
  int blk=(bid&7)*128 + (bid>>3);     // XCD-chunked bijective swizzle (1024%8==0)
  int b=blk>>7; int rem=blk&127;
  int zt=rem>>4, yt=(rem>>2)&3, xt=rem&3;
  int z0=zt*4, y0=yt*8, x0=xt*8;
  const short* gbase = gin + (size_t)b*R3*CH;

  int lane=tid&63, zl=tid>>6;
  int r15=lane&15, g=lane>>4;
  int ix=r15&7, iy=r15>>3;

  float4_ acc[4][4];
  #pragma unroll
  for(int mf=0;mf<4;mf++)
    #pragma unroll
    for(int nf=0;nf<4;nf++) acc[mf][nf]=(float4_){0.f,0.f,0.f,0.f};

  short8* s8=(short8*)in_s;

  // ---- stage 6z x 10y x 10x halo, ALL 64 ci (8 cb of 8), single pass ----
  for(int it=0; it<19; it++){
    int e=tid+it*256;
    if(e<4800){
      int ss=e>>3, cb=e&7;
      int z=ss/100, r2=ss-z*100, y=r2/10, x=r2-y*10;
      int gz=z0-1+z, gy=y0-1+y, gx=x0-1+x;
      short8 v={0,0,0,0,0,0,0,0};
      if(((unsigned)gz<32u)&&((unsigned)gy<32u)&&((unsigned)gx<32u))
        v=*(const short8*)(gbase + ((gz<<10)+(gy<<5)+gx)*CH + cb*8);
      s8[cb*SS3+ss]=v;
    }
  }
  __syncthreads();

  const short8* wb = ((const short8*)wt3) + lane;
  short8 bw0[8], bw1[8], aA[8], aB[8];
  #pragma unroll
  for(int f=0;f<8;f++) bw0[f]=wb[f*64];
  #pragma unroll
  for(int f=0;f<8;f++) bw1[f]=wb[512+f*64];
  // preload A for tap 0: cell = zl*100 + (mf*2+iy)*10 + ix
  #pragma unroll
  for(int ks=0;ks<2;ks++)
    #pragma unroll
    for(int mf=0;mf<4;mf++)
      aA[ks*4+mf]=s8[(ks*4+g)*SS3 + zl*100 + (mf*2+iy)*10 + ix];

  for(int tt=0; tt<27; tt+=2){
    if(tt+1<27){
      int t1=tt+1, kz=t1/9, r=t1-kz*9, ky=r/3, kx=r-ky*3;
      #pragma unroll
      for(int ks=0;ks<2;ks++)
        #pragma unroll
        for(int mf=0;mf<4;mf++)
          aB[ks*4+mf]=s8[(ks*4+g)*SS3 + (zl+kz)*100 + (mf*2+iy+ky)*10 + ix+kx];
    }
    CONV_TAP(aA, bw0);
    if(tt+2<27){
      #pragma unroll
      for(int f=0;f<8;f++) bw0[f]=wb[(tt+2)*512+f*64];
    }
    if(tt+1<27){
      if(tt+2<27){
        int t2=tt+2, kz=t2/9, r=t2-kz*9, ky=r/3, kx=r-ky*3;
        #pragma unroll
        for(int ks=0;ks<2;ks++)
          #pragma unroll
          for(int mf=0;mf<4;mf++)
            aA[ks*4+mf]=s8[(ks*4+g)*SS3 + (zl+kz)*100 + (mf*2+iy+ky)*10 + ix+kx];
      }
      CONV_TAP(aB, bw1);
      if(tt+3<27){
        #pragma unroll
        for(int f=0;f<8;f++) bw1[f]=wb[(tt+3)*512+f*64];
      }
    }
  }

  // ---- epilogue: bias + BN + leaky -> LDS bf16 repack -> coalesced stores ----
  __syncthreads();
  short* ot=(short*)in_s;             // [256 cells][stride 72] = 36864 B
  #pragma unroll
  for(int nf=0;nf<4;nf++){
    int oc=nf*16+r15;
    float iv=bg[oc]/sqrtf(bv[oc]+BNEPS);
    float sh=bias[oc]*iv + bb[oc]-bm[oc]*iv;
    #pragma unroll
    for(int mf=0;mf<4;mf++){
      #pragma unroll
      for(int q=0;q<4;q++){
        int m=mf*16+g*4+q;            // y=m>>3, x=m&7
        float val=acc[mf][nf][q]*iv+sh;
        val = val>=0.f ? val : LEAK*val;
        ot[(zl*64+m)*72 + oc]=f2bf(val);
      }
    }
  }
  __syncthreads();
  short* go = gout + (size_t)b*R3*CH;
  #pragma unroll
  for(int it=0;it<8;it++){
    int e=tid+it*256;
    int vr=e>>3, j=e&7;
    int zz=vr>>6, rr=vr&63;
    short8 v=*(short8*)(ot + vr*72 + j*8);
    *(short8*)(go + ((size_t)((z0+zz)*1024 + (y0+(rr>>3))*32 + x0+(rr&7)))*CH + j*8)=v;
  }
}

// ------- point MLP + fused GN partial stats (XOR-swizzled ft, py [b][n][64]) -------
__global__ __launch_bounds__(256,2) void k_ptgemm(
    const float* __restrict__ feat, const float* __restrict__ w,
    const float* __restrict__ bias, float* __restrict__ y,
    float* __restrict__ stp){
  __shared__ float ws_[64*64];
  __shared__ float ft[64*64];
  __shared__ float sg[8], qg[8];
  int tid=threadIdx.x;
  int blk=blockIdx.x;
  int b=blk>>6, n0=(blk&63)*64;
  for(int e=tid;e<4096;e+=256) ws_[e]=w[e];
  for(int e=tid;e<4096;e+=256){
    int c=e>>6, nl=e&63;
    ft[nl*64 + (c ^ ((nl&7)<<2))]=feat[(size_t)(b*CH+c)*NP + n0+nl];
  }
  if(tid<8){ sg[tid]=0.f; qg[tid]=0.f; }
  __syncthreads();
  int nl=tid&63, qq=tid>>6;
  float av[16];
  #pragma unroll
  for(int j=0;j<16;j++) av[j]=bias[qq*16+j];
  for(int c4=0;c4<64;c4+=4){
    float4_ fv=*(float4_*)&ft[nl*64 + (c4 ^ ((nl&7)<<2))];
    #pragma unroll
    for(int j=0;j<16;j++){
      float4_ wv4=*(float4_*)&ws_[(qq*16+j)*64+c4];
      av[j]=fmaf(fv[0],wv4[0],fmaf(fv[1],wv4[1],fmaf(fv[2],wv4[2],fmaf(fv[3],wv4[3],av[j]))));
    }
  }
  float* yp = y + ((size_t)(b*NP+n0+nl))*64 + qq*16;
  #pragma unroll
  for(int q4=0;q4<4;q4++)
    *(float4_*)(yp+q4*4)=(float4_){av[q4*4+0],av[q4*4+1],av[q4*4+2],av[q4*4+3]};
  float ps[2]={0.f,0.f}, pq[2]={0.f,0.f};
  #pragma unroll
  for(int j=0;j<16;j++){
    int gi=j>>3;
    ps[gi]+=av[j]; pq[gi]+=av[j]*av[j];
  }
  #pragma unroll
  for(int off=32;off>0;off>>=1){
    ps[0]+=__shfl_down(ps[0],off,64); pq[0]+=__shfl_down(pq[0],off,64);
    ps[1]+=__shfl_down(ps[1],off,64); pq[1]+=__shfl_down(pq[1],off,64);
  }
  if((tid&63)==0){
    atomicAdd(&sg[qq*2+0],ps[0]); atomicAdd(&qg[qq*2+0],pq[0]);
    atomicAdd(&sg[qq*2+1],ps[1]); atomicAdd(&qg[qq*2+1],pq[1]);
  }
  __syncthreads();
  if(tid<8){
    atomicAdd(&stp[(b*8+tid)*2+0], sg[tid]);
    atomicAdd(&stp[(b*8+tid)*2+1], qg[tid]);
  }
}

// ------- devoxelize + GN finalize + affine + swish + add; coalesced out -------
__global__ void k_fuse(const short* __restrict__ grid, const float* __restrict__ nc,
                       const float* __restrict__ py, const float* __restrict__ stp,
                       const float* __restrict__ gg, const float* __restrict__ gb,
                       float* __restrict__ out){
  __shared__ float ot[64][65];
  __shared__ float gmu[8], grs[8];
  int tid=threadIdx.x;
  int blk=blockIdx.x;
  int b=blk>>6, n0=(blk&63)*64;
  int nl=tid>>2, qq=tid&3;
  int n=n0+nl;

  if(tid<8){
    float s=stp[(b*8+tid)*2+0], q=stp[(b*8+tid)*2+1];
    float mu=s/(8.f*NP);
    float var=q/(8.f*NP)-mu*mu;
    gmu[tid]=mu;
    grs[tid]=1.0f/sqrtf(var+GNEPS);
  }
  __syncthreads();

  float d_[3]; int i0[3], i1[3];
  #pragma unroll
  for(int dd=0;dd<3;dd++){
    float c=nc[(b*3+dd)*NP+n];
    c=fminf(fmaxf(c,0.f),31.f);
    float f=floorf(c);
    d_[dd]=c-f;
    i0[dd]=(int)f;
    i1[dd]=min(i0[dd]+1,31);
  }
  int idx8[8]; float w8[8];
  #pragma unroll
  for(int k=0;k<8;k++){
    int xx=(k&4)?i1[0]:i0[0];
    int yy=(k&2)?i1[1]:i0[1];
    int zz=(k&1)?i1[2]:i0[2];
    float wx=(k&4)?d_[0]:(1.f-d_[0]);
    float wy=(k&2)?d_[1]:(1.f-d_[1]);
    float wz=(k&1)?d_[2]:(1.f-d_[2]);
    idx8[k]=xx*1024+yy*32+zz;
    w8[k]=wx*wy*wz;
  }
  const short* gbase = grid + (size_t)b*R3*CH;
  const float* pp = py + ((size_t)(b*NP+n))*64;
  #pragma unroll
  for(int c8=0;c8<2;c8++){
    int c0=qq*16+c8*8;
    float dv[8]={0.f,0.f,0.f,0.f,0.f,0.f,0.f,0.f};
    #pragma unroll
    for(int k=0;k<8;k++){
      short8 gv=*(const short8*)(gbase + (size_t)idx8[k]*CH + c0);
      #pragma unroll
      for(int j=0;j<8;j++) dv[j]+=w8[k]*bf2f(gv[j]);
    }
    float4_ p0=*(const float4_*)(pp+c0);
    float4_ p1=*(const float4_*)(pp+c0+4);
    #pragma unroll
    for(int j=0;j<8;j++){
      int c=c0+j;
      float pv = j<4 ? p0[j] : p1[j-4];
      float yn=(pv-gmu[c>>3])*grs[c>>3]*gg[c]+gb[c];
      float sw=yn/(1.f+expf(-yn));
      ot[c][nl]=dv[j]+sw;
    }
  }
  __syncthreads();
  for(int i=tid;i<1024;i+=256){
    int c=i>>4, sg=i&15;
    float4_ v={ot[c][sg*4+0],ot[c][sg*4+1],ot[c][sg*4+2],ot[c][sg*4+3]};
    *(float4_*)(out + (size_t)(b*CH+c)*NP + n0 + sg*4) = v;
  }
}

// ---------------- merged passthrough copy (coords + temb) ----------------
__global__ void k_copyall(const float* __restrict__ coords, const float* __restrict__ temb,
                          float* __restrict__ out){
  int t=blockIdx.x*256+threadIdx.x;
  if(t<98304) out[2097152+t]=coords[t];
  else if(t<98816) out[2195456+(t-98304)]=temb[t-98304];
}

extern "C" void kernel_launch(void* const* d_in, const int* in_sizes, int n_in,
                              void* d_out, int out_size, void* d_ws, size_t ws_size,
                              hipStream_t stream){
  const float* features=(const float*)d_in[0];
  const float* coords  =(const float*)d_in[1];
  const float* temb    =(const float*)d_in[2];
  const float* c1w=(const float*)d_in[3];
  const float* c1b=(const float*)d_in[4];
  const float* b1g=(const float*)d_in[5];
  const float* b1b=(const float*)d_in[6];
  const float* b1m=(const float*)d_in[7];
  const float* b1v=(const float*)d_in[8];
  const float* c2w=(const float*)d_in[9];
  const float* c2b=(const float*)d_in[10];
  const float* b2g=(const float*)d_in[11];
  const float* b2b=(const float*)d_in[12];
  const float* b2m=(const float*)d_in[13];
  const float* b2v=(const float*)d_in[14];
  const float* pfw=(const float*)d_in[15];
  const float* pfb=(const float*)d_in[16];
  const float* gng=(const float*)d_in[17];
  const float* gnb=(const float*)d_in[18];

  float* F=(float*)d_ws;
  float* ms  = F + 0;                   // 32
  float* nc  = F + 32;                  // 98304
  int*   vi  = (int*)(F + 98336);       // 32768
  short* w1t = (short*)(F + 131104);    // 110592 sh = 55296 f
  short* w2t = (short*)(F + 186400);    // 55296 f
  float* py  = F + 241696;              // 2097152  ([b][n][64] layout)
  float* stp = F + 2338848;             // 128  (memset start)
  float* cnt = F + 2338976;             // 262144
  float* gA  = F + 2601120;             // 16777216 (zeroed sparsely by k_assignzero)
  short* gBF1= (short*)(F + 19378336);  // 16777216 sh = 8388608 f
  short* gBF2= (short*)(F + 27766944);  // 8388608 f
  float* out=(float*)d_out;

  static bool attr_set=false;
  if(!attr_set){
    hipFuncSetAttribute((const void*)k_conv_mfma,
                        hipFuncAttributeMaxDynamicSharedMemorySize, 77056);
    attr_set=true;
  }

  hipMemsetAsync(stp, 0, (size_t)(128+262144)*4, stream);   // stp + cnt only

  k_voxstats <<<8,256,0,stream>>>(coords, ms);
  k_assignzero<<<8192,256,0,stream>>>(coords, ms, nc, vi, gA);
  k_scatter  <<<512,256,0,stream>>>(features, vi, gA, cnt);
  k_gridmean <<<8192,256,0,stream>>>(gA, cnt, gBF1);
  k_wt3x2    <<<864,256,0,stream>>>(c1w, c2w, w1t, w2t);
  k_conv_mfma<<<1024,256,77056,stream>>>(gBF1, gBF2, w1t, c1b, b1g, b1b, b1m, b1v);
  k_conv_mfma<<<1024,256,77056,stream>>>(gBF2, gBF1, w2t, c2b, b2g, b2b, b2m, b2v);
  k_ptgemm   <<<512,256,0,stream>>>(features, pfw, pfb, py, stp);
  k_fuse     <<<512,256,0,stream>>>(gBF1, nc, py, stp, gng, gnb, out);
  k_copyall  <<<386,256,0,stream>>>(coords, temb, out);
}

// Round 20
// 188.864 us; speedup vs baseline: 1.0177x; 1.0177x over previous
//
#include <hip/hip_runtime.h>
#include <hip/hip_bf16.h>
#include <math.h>

#define BB 8
#define CH 64
#define NP 4096
#define RG 32
#define R3 32768
#define LEAK 0.2f
#define BNEPS 1e-5f
#define GNEPS 1e-5f
#define SS3 602   // LDS cb-region stride (16B units) for 600-cell halo; %8==2

typedef short short8 __attribute__((ext_vector_type(8)));
typedef float float4_ __attribute__((ext_vector_type(4)));

__device__ __forceinline__ short f2bf(float f){
  unsigned u = __float_as_uint(f);
  u += 0x7FFF + ((u>>16)&1);          // RNE
  return (short)(u>>16);
}
__device__ __forceinline__ float bf2f(short s){
  unsigned u = ((unsigned)(unsigned short)s)<<16;
  return __uint_as_float(u);
}

// ---------------- voxelize stats ----------------
__global__ void k_voxstats(const float* __restrict__ coords, float* __restrict__ ms){
  int b = blockIdx.x;
  __shared__ float red[256];
  float mean[3];
  for(int d=0; d<3; d++){
    float s=0.f;
    for(int i=threadIdx.x; i<NP; i+=256) s += coords[(b*3+d)*NP+i];
    red[threadIdx.x]=s; __syncthreads();
    for(int o=128;o>0;o>>=1){ if(threadIdx.x<o) red[threadIdx.x]+=red[threadIdx.x+o]; __syncthreads(); }
    mean[d]=red[0]/(float)NP; __syncthreads();
  }
  float mx=0.f;
  for(int i=threadIdx.x; i<NP; i+=256){
    float x=coords[(b*3+0)*NP+i]-mean[0];
    float y=coords[(b*3+1)*NP+i]-mean[1];
    float z=coords[(b*3+2)*NP+i]-mean[2];
    mx=fmaxf(mx, sqrtf(x*x+y*y+z*z));
  }
  red[threadIdx.x]=mx; __syncthreads();
  for(int o=128;o>0;o>>=1){ if(threadIdx.x<o) red[threadIdx.x]=fmaxf(red[threadIdx.x],red[threadIdx.x+o]); __syncthreads(); }
  if(threadIdx.x==0){
    ms[b*4+0]=mean[0]; ms[b*4+1]=mean[1]; ms[b*4+2]=mean[2];
    ms[b*4+3]=red[0]*2.0f;
  }
}

// ------- fused: norm coords + voxel index + zero touched voxels -------
// XCD-affinity: 8192 blocks, batch = swz>>10 = bid&7
__global__ void k_assignzero(const float* __restrict__ coords, const float* __restrict__ ms,
                             float* __restrict__ nc, int* __restrict__ vi,
                             float* __restrict__ gsum){
  int bid=blockIdx.x;
  int blk=(bid&7)*1024 + (bid>>3);
  int wid = (blk*256+threadIdx.x)>>6;
  int lane = threadIdx.x&63;
  if(wid>=BB*NP) return;
  int b=wid>>12, n=wid&4095;
  float scale=ms[b*4+3];
  float v[3]; int vox[3];
  #pragma unroll
  for(int d=0; d<3; d++){
    float c=coords[(b*3+d)*NP+n] - ms[b*4+d];
    float vv=(c/scale + 0.5f)*32.0f;
    vv=fminf(fmaxf(vv,0.0f),31.0f);
    v[d]=vv;
    vox[d]=(int)rintf(vv);
  }
  int idx=vox[0]*1024+vox[1]*32+vox[2];
  if(lane<3) nc[(b*3+lane)*NP+n]=v[lane];
  if(lane==0) vi[wid]=idx;
  gsum[((size_t)b*R3+idx)*CH + lane]=0.f;
}

// --------- scatter: LDS-transposed feat tile, wave-per-point atomics ----------
// XCD-affinity: 512 blocks, batch = swz>>6 = bid&7
__global__ __launch_bounds__(256,2) void k_scatter(
    const float* __restrict__ feat, const int* __restrict__ vi,
    float* __restrict__ gsum, float* __restrict__ cnt){
  __shared__ float ft[64][65];
  int tid=threadIdx.x;
  int bid=blockIdx.x;
  int blk=(bid&7)*64 + (bid>>3);
  int b=blk>>6, n0=(blk&63)*64;
  for(int e=tid;e<4096;e+=256){
    int c=e>>6, nl=e&63;
    ft[nl][c]=feat[(size_t)(b*CH+c)*NP + n0+nl];
  }
  __syncthreads();
  int lane=tid&63, wv=tid>>6;
  for(int p=wv;p<64;p+=4){
    int idx=vi[(b<<12)+n0+p];
    atomicAdd(gsum + ((size_t)b*R3+idx)*CH + lane, ft[p][lane]);
    if(lane==0) atomicAdd(&cnt[b*R3+idx], 1.0f);
  }
}

// ------- sums -> means, cnt-guarded; XCD-affinity: batch = bid&7 -------
__global__ void k_gridmean(const float* __restrict__ gsum, const float* __restrict__ cnt,
                           short* __restrict__ gbf){
  int bid=blockIdx.x;
  int blk=(bid&7)*1024 + (bid>>3);
  int t=blk*256+threadIdx.x;
  if(t>=BB*R3*8) return;
  int v=t>>3, q=t&7;
  float c=cnt[v];
  short8 o={0,0,0,0,0,0,0,0};
  if(c!=0.f){
    float inv=1.0f/c;
    const float* sp=gsum + (size_t)v*CH + q*8;
    #pragma unroll
    for(int j=0;j<8;j++) o[j]=f2bf(sp[j]*inv);
  }
  ((short8*)gbf)[(size_t)v*8+q]=o;
}

// ------- both conv weights -> per-fragment contiguous bf16 -------
__global__ void k_wt3x2(const float* __restrict__ wa, const float* __restrict__ wb,
                        short* __restrict__ oa, short* __restrict__ ob){
  int t=blockIdx.x*256+threadIdx.x;
  if(t>=2*CH*CH*27) return;
  const float* w = (t<CH*CH*27)? wa : wb;
  short* o = (t<CH*CH*27)? oa : ob;
  int tt = (t<CH*CH*27)? t : t-CH*CH*27;
  int frag=tt>>9, l=(tt>>3)&63, j=tt&7;
  int tap=frag>>3, hh=(frag>>2)&1, nf=frag&3;
  int oc=nf*16+(l&15);
  int ci=hh*32+(l>>4)*8+j;
  o[tt]=f2bf(w[oc*1728 + ci*27 + tap]);
}

// ------------- MFMA implicit-GEMM 3x3x3 conv + bias + BN + leaky -------------
// tile 4z x 8y x 8x (256 cells), 4 waves (wave = z-layer, M=64 cells/wave).
// ALL 64 ci staged once: 77 KB DYNAMIC LDS -> 2 blocks/CU. batch = bid&7.
#define CONV_TAP(AF, BW) \
  _Pragma("unroll") for(int ks=0;ks<2;ks++) \
    _Pragma("unroll") for(int mf=0;mf<4;mf++) \
      _Pragma("unroll") for(int nf=0;nf<4;nf++) \
        acc[mf][nf]=__builtin_amdgcn_mfma_f32_16x16x32_bf16(AF[ks*4+mf],BW[ks*4+nf],acc[mf][nf],0,0,0);

__global__ __launch_bounds__(256,2) void k_conv_mfma(
    const short* __restrict__ gin, short* __restrict__ gout,
    const short* __restrict__ wt3, const float* __restrict__ bias,
    const float* __restrict__ bg, const float* __restrict__ bb,
    const float* __restrict__ bm, const float* __restrict__ bv){
  extern __shared__ __align__(16) short in_s[];   // 8*SS3*8 shorts = 77056 B
  int tid=threadIdx.x;
  int bid=blockIdx.x;
  int blk=(bid&7)*128 + (bid>>3);     // XCD-chunked bijective swizzle (1024%8==0)
  int b=blk>>7; int rem=blk&127;
  int zt=rem>>4, yt=(rem>>2)&3, xt=rem&3;
  int z0=zt*4, y0=yt*8, x0=xt*8;
  const short* gbase = gin + (size_t)b*R3*CH;

  int lane=tid&63, zl=tid>>6;
  int r15=lane&15, g=lane>>4;
  int ix=r15&7, iy=r15>>3;

  float4_ acc[4][4];
  #pragma unroll
  for(int mf=0;mf<4;mf++)
    #pragma unroll
    for(int nf=0;nf<4;nf++) acc[mf][nf]=(float4_){0.f,0.f,0.f,0.f};

  short8* s8=(short8*)in_s;

  // ---- stage 6z x 10y x 10x halo, ALL 64 ci (8 cb of 8), single pass ----
  for(int it=0; it<19; it++){
    int e=tid+it*256;
    if(e<4800){
      int ss=e>>3, cb=e&7;
      int z=ss/100, r2=ss-z*100, y=r2/10, x=r2-y*10;
      int gz=z0-1+z, gy=y0-1+y, gx=x0-1+x;
      short8 v={0,0,0,0,0,0,0,0};
      if(((unsigned)gz<32u)&&((unsigned)gy<32u)&&((unsigned)gx<32u))
        v=*(const short8*)(gbase + ((gz<<10)+(gy<<5)+gx)*CH + cb*8);
      s8[cb*SS3+ss]=v;
    }
  }
  __syncthreads();

  const short8* wb = ((const short8*)wt3) + lane;
  short8 bw0[8], bw1[8], aA[8], aB[8];
  #pragma unroll
  for(int f=0;f<8;f++) bw0[f]=wb[f*64];
  #pragma unroll
  for(int f=0;f<8;f++) bw1[f]=wb[512+f*64];
  // preload A for tap 0: cell = zl*100 + (mf*2+iy)*10 + ix
  #pragma unroll
  for(int ks=0;ks<2;ks++)
    #pragma unroll
    for(int mf=0;mf<4;mf++)
      aA[ks*4+mf]=s8[(ks*4+g)*SS3 + zl*100 + (mf*2+iy)*10 + ix];

  for(int tt=0; tt<27; tt+=2){
    if(tt+1<27){
      int t1=tt+1, kz=t1/9, r=t1-kz*9, ky=r/3, kx=r-ky*3;
      #pragma unroll
      for(int ks=0;ks<2;ks++)
        #pragma unroll
        for(int mf=0;mf<4;mf++)
          aB[ks*4+mf]=s8[(ks*4+g)*SS3 + (zl+kz)*100 + (mf*2+iy+ky)*10 + ix+kx];
    }
    CONV_TAP(aA, bw0);
    if(tt+2<27){
      #pragma unroll
      for(int f=0;f<8;f++) bw0[f]=wb[(tt+2)*512+f*64];
    }
    if(tt+1<27){
      if(tt+2<27){
        int t2=tt+2, kz=t2/9, r=t2-kz*9, ky=r/3, kx=r-ky*3;
        #pragma unroll
        for(int ks=0;ks<2;ks++)
          #pragma unroll
          for(int mf=0;mf<4;mf++)
            aA[ks*4+mf]=s8[(ks*4+g)*SS3 + (zl+kz)*100 + (mf*2+iy+ky)*10 + ix+kx];
      }
      CONV_TAP(aB, bw1);
      if(tt+3<27){
        #pragma unroll
        for(int f=0;f<8;f++) bw1[f]=wb[(tt+3)*512+f*64];
      }
    }
  }

  // ---- epilogue: bias + BN + leaky -> LDS bf16 repack -> coalesced stores ----
  __syncthreads();
  short* ot=(short*)in_s;             // [256 cells][stride 72] = 36864 B
  #pragma unroll
  for(int nf=0;nf<4;nf++){
    int oc=nf*16+r15;
    float iv=bg[oc]/sqrtf(bv[oc]+BNEPS);
    float sh=bias[oc]*iv + bb[oc]-bm[oc]*iv;
    #pragma unroll
    for(int mf=0;mf<4;mf++){
      #pragma unroll
      for(int q=0;q<4;q++){
        int m=mf*16+g*4+q;            // y=m>>3, x=m&7
        float val=acc[mf][nf][q]*iv+sh;
        val = val>=0.f ? val : LEAK*val;
        ot[(zl*64+m)*72 + oc]=f2bf(val);
      }
    }
  }
  __syncthreads();
  short* go = gout + (size_t)b*R3*CH;
  #pragma unroll
  for(int it=0;it<8;it++){
    int e=tid+it*256;
    int vr=e>>3, j=e&7;
    int zz=vr>>6, rr=vr&63;
    short8 v=*(short8*)(ot + vr*72 + j*8);
    *(short8*)(go + ((size_t)((z0+zz)*1024 + (y0+(rr>>3))*32 + x0+(rr&7)))*CH + j*8)=v;
  }
}

// ------- point MLP + fused GN partial stats; XCD-affinity batch = bid&7 -------
__global__ __launch_bounds__(256,2) void k_ptgemm(
    const float* __restrict__ feat, const float* __restrict__ w,
    const float* __restrict__ bias, float* __restrict__ y,
    float* __restrict__ stp){
  __shared__ float ws_[64*64];
  __shared__ float ft[64*64];
  __shared__ float sg[8], qg[8];
  int tid=threadIdx.x;
  int bid=blockIdx.x;
  int blk=(bid&7)*64 + (bid>>3);
  int b=blk>>6, n0=(blk&63)*64;
  for(int e=tid;e<4096;e+=256) ws_[e]=w[e];
  for(int e=tid;e<4096;e+=256){
    int c=e>>6, nl=e&63;
    ft[nl*64 + (c ^ ((nl&7)<<2))]=feat[(size_t)(b*CH+c)*NP + n0+nl];
  }
  if(tid<8){ sg[tid]=0.f; qg[tid]=0.f; }
  __syncthreads();
  int nl=tid&63, qq=tid>>6;
  float av[16];
  #pragma unroll
  for(int j=0;j<16;j++) av[j]=bias[qq*16+j];
  for(int c4=0;c4<64;c4+=4){
    float4_ fv=*(float4_*)&ft[nl*64 + (c4 ^ ((nl&7)<<2))];
    #pragma unroll
    for(int j=0;j<16;j++){
      float4_ wv4=*(float4_*)&ws_[(qq*16+j)*64+c4];
      av[j]=fmaf(fv[0],wv4[0],fmaf(fv[1],wv4[1],fmaf(fv[2],wv4[2],fmaf(fv[3],wv4[3],av[j]))));
    }
  }
  float* yp = y + ((size_t)(b*NP+n0+nl))*64 + qq*16;
  #pragma unroll
  for(int q4=0;q4<4;q4++)
    *(float4_*)(yp+q4*4)=(float4_){av[q4*4+0],av[q4*4+1],av[q4*4+2],av[q4*4+3]};
  float ps[2]={0.f,0.f}, pq[2]={0.f,0.f};
  #pragma unroll
  for(int j=0;j<16;j++){
    int gi=j>>3;
    ps[gi]+=av[j]; pq[gi]+=av[j]*av[j];
  }
  #pragma unroll
  for(int off=32;off>0;off>>=1){
    ps[0]+=__shfl_down(ps[0],off,64); pq[0]+=__shfl_down(pq[0],off,64);
    ps[1]+=__shfl_down(ps[1],off,64); pq[1]+=__shfl_down(pq[1],off,64);
  }
  if((tid&63)==0){
    atomicAdd(&sg[qq*2+0],ps[0]); atomicAdd(&qg[qq*2+0],pq[0]);
    atomicAdd(&sg[qq*2+1],ps[1]); atomicAdd(&qg[qq*2+1],pq[1]);
  }
  __syncthreads();
  if(tid<8){
    atomicAdd(&stp[(b*8+tid)*2+0], sg[tid]);
    atomicAdd(&stp[(b*8+tid)*2+1], qg[tid]);
  }
}

// ------- devoxelize + GN finalize + affine + swish + add; batch = bid&7 -------
__global__ void k_fuse(const short* __restrict__ grid, const float* __restrict__ nc,
                       const float* __restrict__ py, const float* __restrict__ stp,
                       const float* __restrict__ gg, const float* __restrict__ gb,
                       float* __restrict__ out){
  __shared__ float ot[64][65];
  __shared__ float gmu[8], grs[8];
  int tid=threadIdx.x;
  int bid=blockIdx.x;
  int blk=(bid&7)*64 + (bid>>3);
  int b=blk>>6, n0=(blk&63)*64;
  int nl=tid>>2, qq=tid&3;
  int n=n0+nl;

  if(tid<8){
    float s=stp[(b*8+tid)*2+0], q=stp[(b*8+tid)*2+1];
    float mu=s/(8.f*NP);
    float var=q/(8.f*NP)-mu*mu;
    gmu[tid]=mu;
    grs[tid]=1.0f/sqrtf(var+GNEPS);
  }
  __syncthreads();

  float d_[3]; int i0[3], i1[3];
  #pragma unroll
  for(int dd=0;dd<3;dd++){
    float c=nc[(b*3+dd)*NP+n];
    c=fminf(fmaxf(c,0.f),31.f);
    float f=floorf(c);
    d_[dd]=c-f;
    i0[dd]=(int)f;
    i1[dd]=min(i0[dd]+1,31);
  }
  int idx8[8]; float w8[8];
  #pragma unroll
  for(int k=0;k<8;k++){
    int xx=(k&4)?i1[0]:i0[0];
    int yy=(k&2)?i1[1]:i0[1];
    int zz=(k&1)?i1[2]:i0[2];
    float wx=(k&4)?d_[0]:(1.f-d_[0]);
    float wy=(k&2)?d_[1]:(1.f-d_[1]);
    float wz=(k&1)?d_[2]:(1.f-d_[2]);
    idx8[k]=xx*1024+yy*32+zz;
    w8[k]=wx*wy*wz;
  }
  const short* gbase = grid + (size_t)b*R3*CH;
  const float* pp = py + ((size_t)(b*NP+n))*64;
  #pragma unroll
  for(int c8=0;c8<2;c8++){
    int c0=qq*16+c8*8;
    float dv[8]={0.f,0.f,0.f,0.f,0.f,0.f,0.f,0.f};
    #pragma unroll
    for(int k=0;k<8;k++){
      short8 gv=*(const short8*)(gbase + (size_t)idx8[k]*CH + c0);
      #pragma unroll
      for(int j=0;j<8;j++) dv[j]+=w8[k]*bf2f(gv[j]);
    }
    float4_ p0=*(const float4_*)(pp+c0);
    float4_ p1=*(const float4_*)(pp+c0+4);
    #pragma unroll
    for(int j=0;j<8;j++){
      int c=c0+j;
      float pv = j<4 ? p0[j] : p1[j-4];
      float yn=(pv-gmu[c>>3])*grs[c>>3]*gg[c]+gb[c];
      float sw=yn/(1.f+expf(-yn));
      ot[c][nl]=dv[j]+sw;
    }
  }
  __syncthreads();
  for(int i=tid;i<1024;i+=256){
    int c=i>>4, sg=i&15;
    float4_ v={ot[c][sg*4+0],ot[c][sg*4+1],ot[c][sg*4+2],ot[c][sg*4+3]};
    *(float4_*)(out + (size_t)(b*CH+c)*NP + n0 + sg*4) = v;
  }
}

// ---------------- merged passthrough copy (coords + temb) ----------------
__global__ void k_copyall(const float* __restrict__ coords, const float* __restrict__ temb,
                          float* __restrict__ out){
  int t=blockIdx.x*256+threadIdx.x;
  if(t<98304) out[2097152+t]=coords[t];
  else if(t<98816) out[2195456+(t-98304)]=temb[t-98304];
}

extern "C" void kernel_launch(void* const* d_in, const int* in_sizes, int n_in,
                              void* d_out, int out_size, void* d_ws, size_t ws_size,
                              hipStream_t stream){
  const float* features=(const float*)d_in[0];
  const float* coords  =(const float*)d_in[1];
  const float* temb    =(const float*)d_in[2];
  const float* c1w=(const float*)d_in[3];
  const float* c1b=(const float*)d_in[4];
  const float* b1g=(const float*)d_in[5];
  const float* b1b=(const float*)d_in[6];
  const float* b1m=(const float*)d_in[7];
  const float* b1v=(const float*)d_in[8];
  const float* c2w=(const float*)d_in[9];
  const float* c2b=(const float*)d_in[10];
  const float* b2g=(const float*)d_in[11];
  const float* b2b=(const float*)d_in[12];
  const float* b2m=(const float*)d_in[13];
  const float* b2v=(const float*)d_in[14];
  const float* pfw=(const float*)d_in[15];
  const float* pfb=(const float*)d_in[16];
  const float* gng=(const float*)d_in[17];
  const float* gnb=(const float*)d_in[18];

  float* F=(float*)d_ws;
  float* ms  = F + 0;                   // 32
  float* nc  = F + 32;                  // 98304
  int*   vi  = (int*)(F + 98336);       // 32768
  short* w1t = (short*)(F + 131104);    // 110592 sh = 55296 f
  short* w2t = (short*)(F + 186400);    // 55296 f
  float* py  = F + 241696;              // 2097152  ([b][n][64] layout)
  float* stp = F + 2338848;             // 128  (memset start)
  float* cnt = F + 2338976;             // 262144
  float* gA  = F + 2601120;             // 16777216 (zeroed sparsely by k_assignzero)
  short* gBF1= (short*)(F + 19378336);  // 16777216 sh = 8388608 f
  short* gBF2= (short*)(F + 27766944);  // 8388608 f
  float* out=(float*)d_out;

  static bool attr_set=false;
  if(!attr_set){
    hipFuncSetAttribute((const void*)k_conv_mfma,
                        hipFuncAttributeMaxDynamicSharedMemorySize, 77056);
    attr_set=true;
  }

  hipMemsetAsync(stp, 0, (size_t)(128+262144)*4, stream);   // stp + cnt only

  k_voxstats <<<8,256,0,stream>>>(coords, ms);
  k_assignzero<<<8192,256,0,stream>>>(coords, ms, nc, vi, gA);
  k_scatter  <<<512,256,0,stream>>>(features, vi, gA, cnt);
  k_gridmean <<<8192,256,0,stream>>>(gA, cnt, gBF1);
  k_wt3x2    <<<864,256,0,stream>>>(c1w, c2w, w1t, w2t);
  k_conv_mfma<<<1024,256,77056,stream>>>(gBF1, gBF2, w1t, c1b, b1g, b1b, b1m, b1v);
  k_conv_mfma<<<1024,256,77056,stream>>>(gBF2, gBF1, w2t, c2b, b2g, b2b, b2m, b2v);
  k_ptgemm   <<<512,256,0,stream>>>(features, pfw, pfb, py, stp);
  k_fuse     <<<512,256,0,stream>>>(gBF1, nc, py, stp, gng, gnb, out);
  k_copyall  <<<386,256,0,stream>>>(coords, temb, out);
}

// Round 21
// 180.698 us; speedup vs baseline: 1.0637x; 1.0452x over previous
//
#include <hip/hip_runtime.h>
#include <hip/hip_bf16.h>
#include <math.h>

#define BB 8
#define CH 64
#define NP 4096
#define RG 32
#define R3 32768
#define LEAK 0.2f
#define BNEPS 1e-5f
#define GNEPS 1e-5f
#define SS3 602   // LDS cb-region stride (16B units) for 600-cell halo; %8==2

typedef short short8 __attribute__((ext_vector_type(8)));
typedef float float4_ __attribute__((ext_vector_type(4)));

__device__ __forceinline__ short f2bf(float f){
  unsigned u = __float_as_uint(f);
  u += 0x7FFF + ((u>>16)&1);          // RNE
  return (short)(u>>16);
}
__device__ __forceinline__ float bf2f(short s){
  unsigned u = ((unsigned)(unsigned short)s)<<16;
  return __uint_as_float(u);
}

// ---------------- voxelize stats (fused 3-dim mean pass + max pass) ----------------
__global__ void k_voxstats(const float* __restrict__ coords, float* __restrict__ ms){
  int b = blockIdx.x;
  __shared__ float r0[256], r1[256], r2[256];
  float s0=0.f, s1=0.f, s2=0.f;
  const float* cx=coords+(size_t)(b*3+0)*NP;
  const float* cy=coords+(size_t)(b*3+1)*NP;
  const float* cz=coords+(size_t)(b*3+2)*NP;
  for(int i=threadIdx.x; i<NP; i+=256){ s0+=cx[i]; s1+=cy[i]; s2+=cz[i]; }
  r0[threadIdx.x]=s0; r1[threadIdx.x]=s1; r2[threadIdx.x]=s2;
  __syncthreads();
  for(int o=128;o>0;o>>=1){
    if(threadIdx.x<o){
      r0[threadIdx.x]+=r0[threadIdx.x+o];
      r1[threadIdx.x]+=r1[threadIdx.x+o];
      r2[threadIdx.x]+=r2[threadIdx.x+o];
    }
    __syncthreads();
  }
  float m0=r0[0]/(float)NP, m1=r1[0]/(float)NP, m2=r2[0]/(float)NP;
  __syncthreads();
  float mx=0.f;
  for(int i=threadIdx.x; i<NP; i+=256){
    float x=cx[i]-m0, y=cy[i]-m1, z=cz[i]-m2;
    mx=fmaxf(mx, sqrtf(x*x+y*y+z*z));
  }
  r0[threadIdx.x]=mx; __syncthreads();
  for(int o=128;o>0;o>>=1){ if(threadIdx.x<o) r0[threadIdx.x]=fmaxf(r0[threadIdx.x],r0[threadIdx.x+o]); __syncthreads(); }
  if(threadIdx.x==0){
    ms[b*4+0]=m0; ms[b*4+1]=m1; ms[b*4+2]=m2;
    ms[b*4+3]=r0[0]*2.0f;
  }
}

// ------- fused: norm coords + voxel index + zero touched voxels -------
__global__ void k_assignzero(const float* __restrict__ coords, const float* __restrict__ ms,
                             float* __restrict__ nc, int* __restrict__ vi,
                             float* __restrict__ gsum){
  int bid=blockIdx.x;
  int blk=(bid&7)*1024 + (bid>>3);
  int wid = (blk*256+threadIdx.x)>>6;
  int lane = threadIdx.x&63;
  if(wid>=BB*NP) return;
  int b=wid>>12, n=wid&4095;
  float scale=ms[b*4+3];
  float v[3]; int vox[3];
  #pragma unroll
  for(int d=0; d<3; d++){
    float c=coords[(b*3+d)*NP+n] - ms[b*4+d];
    float vv=(c/scale + 0.5f)*32.0f;
    vv=fminf(fmaxf(vv,0.0f),31.0f);
    v[d]=vv;
    vox[d]=(int)rintf(vv);
  }
  int idx=vox[0]*1024+vox[1]*32+vox[2];
  if(lane<3) nc[(b*3+lane)*NP+n]=v[lane];
  if(lane==0) vi[wid]=idx;
  gsum[((size_t)b*R3+idx)*CH + lane]=0.f;
}

// --------- scatter: LDS-transposed feat tile, wave-per-point atomics ----------
__global__ __launch_bounds__(256,2) void k_scatter(
    const float* __restrict__ feat, const int* __restrict__ vi,
    float* __restrict__ gsum, float* __restrict__ cnt){
  __shared__ float ft[64][65];
  int tid=threadIdx.x;
  int bid=blockIdx.x;
  int blk=(bid&7)*64 + (bid>>3);
  int b=blk>>6, n0=(blk&63)*64;
  for(int e=tid;e<4096;e+=256){
    int c=e>>6, nl=e&63;
    ft[nl][c]=feat[(size_t)(b*CH+c)*NP + n0+nl];
  }
  __syncthreads();
  int lane=tid&63, wv=tid>>6;
  for(int p=wv;p<64;p+=4){
    int idx=vi[(b<<12)+n0+p];
    atomicAdd(gsum + ((size_t)b*R3+idx)*CH + lane, ft[p][lane]);
    if(lane==0) atomicAdd(&cnt[b*R3+idx], 1.0f);
  }
}

// ------- sums -> means, cnt-guarded; XCD-affinity -------
__global__ void k_gridmean(const float* __restrict__ gsum, const float* __restrict__ cnt,
                           short* __restrict__ gbf){
  int bid=blockIdx.x;
  int blk=(bid&7)*1024 + (bid>>3);
  int t=blk*256+threadIdx.x;
  if(t>=BB*R3*8) return;
  int v=t>>3, q=t&7;
  float c=cnt[v];
  short8 o={0,0,0,0,0,0,0,0};
  if(c!=0.f){
    float inv=1.0f/c;
    const float* sp=gsum + (size_t)v*CH + q*8;
    #pragma unroll
    for(int j=0;j<8;j++) o[j]=f2bf(sp[j]*inv);
  }
  ((short8*)gbf)[(size_t)v*8+q]=o;
}

// ------- both conv weights -> per-fragment contiguous bf16 -------
__global__ void k_wt3x2(const float* __restrict__ wa, const float* __restrict__ wb,
                        short* __restrict__ oa, short* __restrict__ ob){
  int t=blockIdx.x*256+threadIdx.x;
  if(t>=2*CH*CH*27) return;
  const float* w = (t<CH*CH*27)? wa : wb;
  short* o = (t<CH*CH*27)? oa : ob;
  int tt = (t<CH*CH*27)? t : t-CH*CH*27;
  int frag=tt>>9, l=(tt>>3)&63, j=tt&7;
  int tap=frag>>3, hh=(frag>>2)&1, nf=frag&3;
  int oc=nf*16+(l&15);
  int ci=hh*32+(l>>4)*8+j;
  o[tt]=f2bf(w[oc*1728 + ci*27 + tap]);
}

// ------------- MFMA implicit-GEMM 3x3x3 conv + bias + BN + leaky -------------
// tile 4z x 8y x 8x, 4 waves (M=64/wave), 77 KB dyn LDS, 2 blocks/CU.
// T14 async-stage split: stage z-slices 0-3 -> barrier -> issue slice 4-5 reg
// loads -> compute taps 0-8 (kz=0, slices 0-3 only) -> ds_write pf -> barrier
// -> compute taps 9-26. Hides 1/3 of staging under MFMA.
#define CONV_TAP(AF, BW) \
  _Pragma("unroll") for(int ks=0;ks<2;ks++) \
    _Pragma("unroll") for(int mf=0;mf<4;mf++) \
      _Pragma("unroll") for(int nf=0;nf<4;nf++) \
        acc[mf][nf]=__builtin_amdgcn_mfma_f32_16x16x32_bf16(AF[ks*4+mf],BW[ks*4+nf],acc[mf][nf],0,0,0);

#define CONV_SEG(TT0, TT1) \
  for(int tt=TT0; tt<TT1; tt+=2){ \
    if(tt+1<TT1){ \
      int t1=tt+1, kz=t1/9, r=t1-kz*9, ky=r/3, kx=r-ky*3; \
      _Pragma("unroll") for(int ks=0;ks<2;ks++) \
        _Pragma("unroll") for(int mf=0;mf<4;mf++) \
          aB[ks*4+mf]=s8[(ks*4+g)*SS3 + (zl+kz)*100 + (mf*2+iy+ky)*10 + ix+kx]; \
    } \
    CONV_TAP(aA, bw0); \
    if(tt+2<TT1){ \
      _Pragma("unroll") for(int f=0;f<8;f++) bw0[f]=wb[(tt+2)*512+f*64]; \
    } \
    if(tt+1<TT1){ \
      if(tt+2<TT1){ \
        int t2=tt+2, kz=t2/9, r=t2-kz*9, ky=r/3, kx=r-ky*3; \
        _Pragma("unroll") for(int ks=0;ks<2;ks++) \
          _Pragma("unroll") for(int mf=0;mf<4;mf++) \
            aA[ks*4+mf]=s8[(ks*4+g)*SS3 + (zl+kz)*100 + (mf*2+iy+ky)*10 + ix+kx]; \
      } \
      CONV_TAP(aB, bw1); \
      if(tt+3<TT1){ \
        _Pragma("unroll") for(int f=0;f<8;f++) bw1[f]=wb[(tt+3)*512+f*64]; \
      } \
    } \
  }

__global__ __launch_bounds__(256,2) void k_conv_mfma(
    const short* __restrict__ gin, short* __restrict__ gout,
    const short* __restrict__ wt3, const float* __restrict__ bias,
    const float* __restrict__ bg, const float* __restrict__ bb,
    const float* __restrict__ bm, const float* __restrict__ bv){
  extern __shared__ __align__(16) short in_s[];   // 8*SS3*8 shorts = 77056 B
  int tid=threadIdx.x;
  int bid=blockIdx.x;
  int blk=(bid&7)*128 + (bid>>3);     // XCD-chunked bijective swizzle (1024%8==0)
  int b=blk>>7; int rem=blk&127;
  int zt=rem>>4, yt=(rem>>2)&3, xt=rem&3;
  int z0=zt*4, y0=yt*8, x0=xt*8;
  const short* gbase = gin + (size_t)b*R3*CH;

  int lane=tid&63, zl=tid>>6;
  int r15=lane&15, g=lane>>4;
  int ix=r15&7, iy=r15>>3;

  float4_ acc[4][4];
  #pragma unroll
  for(int mf=0;mf<4;mf++)
    #pragma unroll
    for(int nf=0;nf<4;nf++) acc[mf][nf]=(float4_){0.f,0.f,0.f,0.f};

  short8* s8=(short8*)in_s;

  // ---- stage z-slices 0..3 (cells 0..399, units 0..3199) direct -> LDS ----
  for(int it=0; it<13; it++){
    int e=tid+it*256;
    if(e<3200){
      int ss=e>>3, cb=e&7;
      int z=ss/100, r2=ss-z*100, y=r2/10, x=r2-y*10;
      int gz=z0-1+z, gy=y0-1+y, gx=x0-1+x;
      short8 v={0,0,0,0,0,0,0,0};
      if(((unsigned)gz<32u)&&((unsigned)gy<32u)&&((unsigned)gx<32u))
        v=*(const short8*)(gbase + ((gz<<10)+(gy<<5)+gx)*CH + cb*8);
      s8[cb*SS3+ss]=v;
    }
  }
  __syncthreads();

  // ---- issue z-slices 4..5 (cells 400..599, 1600 units) into registers ----
  short8 pf[7];
  #pragma unroll
  for(int it=0; it<7; it++){
    int u=tid+it*256;
    short8 v={0,0,0,0,0,0,0,0};
    if(u<1600){
      int ss=400+(u>>3), cb=u&7;
      int z=ss/100, r2=ss-z*100, y=r2/10, x=r2-y*10;
      int gz=z0-1+z, gy=y0-1+y, gx=x0-1+x;
      if(((unsigned)gz<32u)&&((unsigned)gy<32u)&&((unsigned)gx<32u))
        v=*(const short8*)(gbase + ((gz<<10)+(gy<<5)+gx)*CH + cb*8);
    }
    pf[it]=v;
  }

  const short8* wb = ((const short8*)wt3) + lane;
  short8 bw0[8], bw1[8], aA[8], aB[8];
  #pragma unroll
  for(int f=0;f<8;f++) bw0[f]=wb[f*64];
  #pragma unroll
  for(int f=0;f<8;f++) bw1[f]=wb[512+f*64];
  #pragma unroll
  for(int ks=0;ks<2;ks++)
    #pragma unroll
    for(int mf=0;mf<4;mf++)
      aA[ks*4+mf]=s8[(ks*4+g)*SS3 + zl*100 + (mf*2+iy)*10 + ix];

  // ---- SEGMENT A: taps 0..8 (kz=0, slices 0..3 only) ----
  CONV_SEG(0, 9);

  // ---- land slices 4..5 from registers, then barrier ----
  #pragma unroll
  for(int it=0; it<7; it++){
    int u=tid+it*256;
    if(u<1600){
      int ss=400+(u>>3), cb=u&7;
      s8[cb*SS3+ss]=pf[it];
    }
  }
  __syncthreads();

  // ---- SEGMENT B preloads: tap 9 (kz=1,ky=0,kx=0), tap 10 ----
  #pragma unroll
  for(int f=0;f<8;f++) bw0[f]=wb[9*512+f*64];
  #pragma unroll
  for(int f=0;f<8;f++) bw1[f]=wb[10*512+f*64];
  #pragma unroll
  for(int ks=0;ks<2;ks++)
    #pragma unroll
    for(int mf=0;mf<4;mf++)
      aA[ks*4+mf]=s8[(ks*4+g)*SS3 + (zl+1)*100 + (mf*2+iy)*10 + ix];

  // ---- SEGMENT B: taps 9..26 ----
  CONV_SEG(9, 27);

  // ---- epilogue: bias + BN + leaky -> LDS bf16 repack -> coalesced stores ----
  __syncthreads();
  short* ot=(short*)in_s;             // [256 cells][stride 72] = 36864 B
  #pragma unroll
  for(int nf=0;nf<4;nf++){
    int oc=nf*16+r15;
    float iv=bg[oc]/sqrtf(bv[oc]+BNEPS);
    float sh=bias[oc]*iv + bb[oc]-bm[oc]*iv;
    #pragma unroll
    for(int mf=0;mf<4;mf++){
      #pragma unroll
      for(int q=0;q<4;q++){
        int m=mf*16+g*4+q;            // y=m>>3, x=m&7
        float val=acc[mf][nf][q]*iv+sh;
        val = val>=0.f ? val : LEAK*val;
        ot[(zl*64+m)*72 + oc]=f2bf(val);
      }
    }
  }
  __syncthreads();
  short* go = gout + (size_t)b*R3*CH;
  #pragma unroll
  for(int it=0;it<8;it++){
    int e=tid+it*256;
    int vr=e>>3, j=e&7;
    int zz=vr>>6, rr=vr&63;
    short8 v=*(short8*)(ot + vr*72 + j*8);
    *(short8*)(go + ((size_t)((z0+zz)*1024 + (y0+(rr>>3))*32 + x0+(rr&7)))*CH + j*8)=v;
  }
}

// ------- point MLP + fused GN partial stats; XCD-affinity -------
__global__ __launch_bounds__(256,2) void k_ptgemm(
    const float* __restrict__ feat, const float* __restrict__ w,
    const float* __restrict__ bias, float* __restrict__ y,
    float* __restrict__ stp){
  __shared__ float ws_[64*64];
  __shared__ float ft[64*64];
  __shared__ float sg[8], qg[8];
  int tid=threadIdx.x;
  int bid=blockIdx.x;
  int blk=(bid&7)*64 + (bid>>3);
  int b=blk>>6, n0=(blk&63)*64;
  for(int e=tid;e<4096;e+=256) ws_[e]=w[e];
  for(int e=tid;e<4096;e+=256){
    int c=e>>6, nl=e&63;
    ft[nl*64 + (c ^ ((nl&7)<<2))]=feat[(size_t)(b*CH+c)*NP + n0+nl];
  }
  if(tid<8){ sg[tid]=0.f; qg[tid]=0.f; }
  __syncthreads();
  int nl=tid&63, qq=tid>>6;
  float av[16];
  #pragma unroll
  for(int j=0;j<16;j++) av[j]=bias[qq*16+j];
  for(int c4=0;c4<64;c4+=4){
    float4_ fv=*(float4_*)&ft[nl*64 + (c4 ^ ((nl&7)<<2))];
    #pragma unroll
    for(int j=0;j<16;j++){
      float4_ wv4=*(float4_*)&ws_[(qq*16+j)*64+c4];
      av[j]=fmaf(fv[0],wv4[0],fmaf(fv[1],wv4[1],fmaf(fv[2],wv4[2],fmaf(fv[3],wv4[3],av[j]))));
    }
  }
  float* yp = y + ((size_t)(b*NP+n0+nl))*64 + qq*16;
  #pragma unroll
  for(int q4=0;q4<4;q4++)
    *(float4_*)(yp+q4*4)=(float4_){av[q4*4+0],av[q4*4+1],av[q4*4+2],av[q4*4+3]};
  float ps[2]={0.f,0.f}, pq[2]={0.f,0.f};
  #pragma unroll
  for(int j=0;j<16;j++){
    int gi=j>>3;
    ps[gi]+=av[j]; pq[gi]+=av[j]*av[j];
  }
  #pragma unroll
  for(int off=32;off>0;off>>=1){
    ps[0]+=__shfl_down(ps[0],off,64); pq[0]+=__shfl_down(pq[0],off,64);
    ps[1]+=__shfl_down(ps[1],off,64); pq[1]+=__shfl_down(pq[1],off,64);
  }
  if((tid&63)==0){
    atomicAdd(&sg[qq*2+0],ps[0]); atomicAdd(&qg[qq*2+0],pq[0]);
    atomicAdd(&sg[qq*2+1],ps[1]); atomicAdd(&qg[qq*2+1],pq[1]);
  }
  __syncthreads();
  if(tid<8){
    atomicAdd(&stp[(b*8+tid)*2+0], sg[tid]);
    atomicAdd(&stp[(b*8+tid)*2+1], qg[tid]);
  }
}

// ------- devoxelize + GN finalize + affine + swish + add; XCD-affinity -------
__global__ void k_fuse(const short* __restrict__ grid, const float* __restrict__ nc,
                       const float* __restrict__ py, const float* __restrict__ stp,
                       const float* __restrict__ gg, const float* __restrict__ gb,
                       float* __restrict__ out){
  __shared__ float ot[64][65];
  __shared__ float gmu[8], grs[8];
  int tid=threadIdx.x;
  int bid=blockIdx.x;
  int blk=(bid&7)*64 + (bid>>3);
  int b=blk>>6, n0=(blk&63)*64;
  int nl=tid>>2, qq=tid&3;
  int n=n0+nl;

  if(tid<8){
    float s=stp[(b*8+tid)*2+0], q=stp[(b*8+tid)*2+1];
    float mu=s/(8.f*NP);
    float var=q/(8.f*NP)-mu*mu;
    gmu[tid]=mu;
    grs[tid]=1.0f/sqrtf(var+GNEPS);
  }
  __syncthreads();

  float d_[3]; int i0[3], i1[3];
  #pragma unroll
  for(int dd=0;dd<3;dd++){
    float c=nc[(b*3+dd)*NP+n];
    c=fminf(fmaxf(c,0.f),31.f);
    float f=floorf(c);
    d_[dd]=c-f;
    i0[dd]=(int)f;
    i1[dd]=min(i0[dd]+1,31);
  }
  int idx8[8]; float w8[8];
  #pragma unroll
  for(int k=0;k<8;k++){
    int xx=(k&4)?i1[0]:i0[0];
    int yy=(k&2)?i1[1]:i0[1];
    int zz=(k&1)?i1[2]:i0[2];
    float wx=(k&4)?d_[0]:(1.f-d_[0]);
    float wy=(k&2)?d_[1]:(1.f-d_[1]);
    float wz=(k&1)?d_[2]:(1.f-d_[2]);
    idx8[k]=xx*1024+yy*32+zz;
    w8[k]=wx*wy*wz;
  }
  const short* gbase = grid + (size_t)b*R3*CH;
  const float* pp = py + ((size_t)(b*NP+n))*64;
  #pragma unroll
  for(int c8=0;c8<2;c8++){
    int c0=qq*16+c8*8;
    float dv[8]={0.f,0.f,0.f,0.f,0.f,0.f,0.f,0.f};
    #pragma unroll
    for(int k=0;k<8;k++){
      short8 gv=*(const short8*)(gbase + (size_t)idx8[k]*CH + c0);
      #pragma unroll
      for(int j=0;j<8;j++) dv[j]+=w8[k]*bf2f(gv[j]);
    }
    float4_ p0=*(const float4_*)(pp+c0);
    float4_ p1=*(const float4_*)(pp+c0+4);
    #pragma unroll
    for(int j=0;j<8;j++){
      int c=c0+j;
      float pv = j<4 ? p0[j] : p1[j-4];
      float yn=(pv-gmu[c>>3])*grs[c>>3]*gg[c]+gb[c];
      float sw=yn/(1.f+expf(-yn));
      ot[c][nl]=dv[j]+sw;
    }
  }
  __syncthreads();
  for(int i=tid;i<1024;i+=256){
    int c=i>>4, sg=i&15;
    float4_ v={ot[c][sg*4+0],ot[c][sg*4+1],ot[c][sg*4+2],ot[c][sg*4+3]};
    *(float4_*)(out + (size_t)(b*CH+c)*NP + n0 + sg*4) = v;
  }
}

// ---------------- merged passthrough copy (coords + temb) ----------------
__global__ void k_copyall(const float* __restrict__ coords, const float* __restrict__ temb,
                          float* __restrict__ out){
  int t=blockIdx.x*256+threadIdx.x;
  if(t<98304) out[2097152+t]=coords[t];
  else if(t<98816) out[2195456+(t-98304)]=temb[t-98304];
}

extern "C" void kernel_launch(void* const* d_in, const int* in_sizes, int n_in,
                              void* d_out, int out_size, void* d_ws, size_t ws_size,
                              hipStream_t stream){
  const float* features=(const float*)d_in[0];
  const float* coords  =(const float*)d_in[1];
  const float* temb    =(const float*)d_in[2];
  const float* c1w=(const float*)d_in[3];
  const float* c1b=(const float*)d_in[4];
  const float* b1g=(const float*)d_in[5];
  const float* b1b=(const float*)d_in[6];
  const float* b1m=(const float*)d_in[7];
  const float* b1v=(const float*)d_in[8];
  const float* c2w=(const float*)d_in[9];
  const float* c2b=(const float*)d_in[10];
  const float* b2g=(const float*)d_in[11];
  const float* b2b=(const float*)d_in[12];
  const float* b2m=(const float*)d_in[13];
  const float* b2v=(const float*)d_in[14];
  const float* pfw=(const float*)d_in[15];
  const float* pfb=(const float*)d_in[16];
  const float* gng=(const float*)d_in[17];
  const float* gnb=(const float*)d_in[18];

  float* F=(float*)d_ws;
  float* ms  = F + 0;                   // 32
  float* nc  = F + 32;                  // 98304
  int*   vi  = (int*)(F + 98336);       // 32768
  short* w1t = (short*)(F + 131104);    // 110592 sh = 55296 f
  short* w2t = (short*)(F + 186400);    // 55296 f
  float* py  = F + 241696;              // 2097152  ([b][n][64] layout)
  float* stp = F + 2338848;             // 128  (memset start)
  float* cnt = F + 2338976;             // 262144
  float* gA  = F + 2601120;             // 16777216 (zeroed sparsely by k_assignzero)
  short* gBF1= (short*)(F + 19378336);  // 16777216 sh = 8388608 f
  short* gBF2= (short*)(F + 27766944);  // 8388608 f
  float* out=(float*)d_out;

  static bool attr_set=false;
  if(!attr_set){
    hipFuncSetAttribute((const void*)k_conv_mfma,
                        hipFuncAttributeMaxDynamicSharedMemorySize, 77056);
    attr_set=true;
  }

  hipMemsetAsync(stp, 0, (size_t)(128+262144)*4, stream);   // stp + cnt only

  k_voxstats <<<8,256,0,stream>>>(coords, ms);
  k_assignzero<<<8192,256,0,stream>>>(coords, ms, nc, vi, gA);
  k_scatter  <<<512,256,0,stream>>>(features, vi, gA, cnt);
  k_gridmean <<<8192,256,0,stream>>>(gA, cnt, gBF1);
  k_wt3x2    <<<864,256,0,stream>>>(c1w, c2w, w1t, w2t);
  k_conv_mfma<<<1024,256,77056,stream>>>(gBF1, gBF2, w1t, c1b, b1g, b1b, b1m, b1v);
  k_conv_mfma<<<1024,256,77056,stream>>>(gBF2, gBF1, w2t, c2b, b2g, b2b, b2m, b2v);
  k_ptgemm   <<<512,256,0,stream>>>(features, pfw, pfb, py, stp);
  k_fuse     <<<512,256,0,stream>>>(gBF1, nc, py, stp, gng, gnb, out);
  k_copyall  <<<386,256,0,stream>>>(coords, temb, out);
}

// Round 22
// 178.718 us; speedup vs baseline: 1.0755x; 1.0111x over previous
//
#include <hip/hip_runtime.h>
#include <hip/hip_bf16.h>
#include <math.h>

#define BB 8
#define CH 64
#define NP 4096
#define RG 32
#define R3 32768
#define LEAK 0.2f
#define BNEPS 1e-5f
#define GNEPS 1e-5f
#define SS3 602   // LDS cb-region stride (16B units) for 600-cell halo; %8==2

typedef short short8 __attribute__((ext_vector_type(8)));
typedef float float4_ __attribute__((ext_vector_type(4)));

__device__ __forceinline__ short f2bf(float f){
  unsigned u = __float_as_uint(f);
  u += 0x7FFF + ((u>>16)&1);          // RNE
  return (short)(u>>16);
}
__device__ __forceinline__ float bf2f(short s){
  unsigned u = ((unsigned)(unsigned short)s)<<16;
  return __uint_as_float(u);
}

// ---------------- voxelize stats (fused 3-dim mean pass + max pass) ----------------
__global__ void k_voxstats(const float* __restrict__ coords, float* __restrict__ ms){
  int b = blockIdx.x;
  __shared__ float r0[256], r1[256], r2[256];
  float s0=0.f, s1=0.f, s2=0.f;
  const float* cx=coords+(size_t)(b*3+0)*NP;
  const float* cy=coords+(size_t)(b*3+1)*NP;
  const float* cz=coords+(size_t)(b*3+2)*NP;
  for(int i=threadIdx.x; i<NP; i+=256){ s0+=cx[i]; s1+=cy[i]; s2+=cz[i]; }
  r0[threadIdx.x]=s0; r1[threadIdx.x]=s1; r2[threadIdx.x]=s2;
  __syncthreads();
  for(int o=128;o>0;o>>=1){
    if(threadIdx.x<o){
      r0[threadIdx.x]+=r0[threadIdx.x+o];
      r1[threadIdx.x]+=r1[threadIdx.x+o];
      r2[threadIdx.x]+=r2[threadIdx.x+o];
    }
    __syncthreads();
  }
  float m0=r0[0]/(float)NP, m1=r1[0]/(float)NP, m2=r2[0]/(float)NP;
  __syncthreads();
  float mx=0.f;
  for(int i=threadIdx.x; i<NP; i+=256){
    float x=cx[i]-m0, y=cy[i]-m1, z=cz[i]-m2;
    mx=fmaxf(mx, sqrtf(x*x+y*y+z*z));
  }
  r0[threadIdx.x]=mx; __syncthreads();
  for(int o=128;o>0;o>>=1){ if(threadIdx.x<o) r0[threadIdx.x]=fmaxf(r0[threadIdx.x],r0[threadIdx.x+o]); __syncthreads(); }
  if(threadIdx.x==0){
    ms[b*4+0]=m0; ms[b*4+1]=m1; ms[b*4+2]=m2;
    ms[b*4+3]=r0[0]*2.0f;
  }
}

// ------- fused: norm coords + voxel index + zero touched voxels -------
__global__ void k_assignzero(const float* __restrict__ coords, const float* __restrict__ ms,
                             float* __restrict__ nc, int* __restrict__ vi,
                             float* __restrict__ gsum){
  int bid=blockIdx.x;
  int blk=(bid&7)*1024 + (bid>>3);
  int wid = (blk*256+threadIdx.x)>>6;
  int lane = threadIdx.x&63;
  if(wid>=BB*NP) return;
  int b=wid>>12, n=wid&4095;
  float scale=ms[b*4+3];
  float v[3]; int vox[3];
  #pragma unroll
  for(int d=0; d<3; d++){
    float c=coords[(b*3+d)*NP+n] - ms[b*4+d];
    float vv=(c/scale + 0.5f)*32.0f;
    vv=fminf(fmaxf(vv,0.0f),31.0f);
    v[d]=vv;
    vox[d]=(int)rintf(vv);
  }
  int idx=vox[0]*1024+vox[1]*32+vox[2];
  if(lane<3) nc[(b*3+lane)*NP+n]=v[lane];
  if(lane==0) vi[wid]=idx;
  gsum[((size_t)b*R3+idx)*CH + lane]=0.f;
}

// --------- scatter: LDS-transposed feat tile, wave-per-point atomics ----------
__global__ __launch_bounds__(256,2) void k_scatter(
    const float* __restrict__ feat, const int* __restrict__ vi,
    float* __restrict__ gsum, float* __restrict__ cnt){
  __shared__ float ft[64][65];
  int tid=threadIdx.x;
  int bid=blockIdx.x;
  int blk=(bid&7)*64 + (bid>>3);
  int b=blk>>6, n0=(blk&63)*64;
  for(int e=tid;e<4096;e+=256){
    int c=e>>6, nl=e&63;
    ft[nl][c]=feat[(size_t)(b*CH+c)*NP + n0+nl];
  }
  __syncthreads();
  int lane=tid&63, wv=tid>>6;
  for(int p=wv;p<64;p+=4){
    int idx=vi[(b<<12)+n0+p];
    atomicAdd(gsum + ((size_t)b*R3+idx)*CH + lane, ft[p][lane]);
    if(lane==0) atomicAdd(&cnt[b*R3+idx], 1.0f);
  }
}

// ------- sums -> means, cnt-guarded; XCD-affinity -------
__global__ void k_gridmean(const float* __restrict__ gsum, const float* __restrict__ cnt,
                           short* __restrict__ gbf){
  int bid=blockIdx.x;
  int blk=(bid&7)*1024 + (bid>>3);
  int t=blk*256+threadIdx.x;
  if(t>=BB*R3*8) return;
  int v=t>>3, q=t&7;
  float c=cnt[v];
  short8 o={0,0,0,0,0,0,0,0};
  if(c!=0.f){
    float inv=1.0f/c;
    const float* sp=gsum + (size_t)v*CH + q*8;
    #pragma unroll
    for(int j=0;j<8;j++) o[j]=f2bf(sp[j]*inv);
  }
  ((short8*)gbf)[(size_t)v*8+q]=o;
}

// ------- both conv weights -> per-fragment contiguous bf16 -------
__global__ void k_wt3x2(const float* __restrict__ wa, const float* __restrict__ wb,
                        short* __restrict__ oa, short* __restrict__ ob){
  int t=blockIdx.x*256+threadIdx.x;
  if(t>=2*CH*CH*27) return;
  const float* w = (t<CH*CH*27)? wa : wb;
  short* o = (t<CH*CH*27)? oa : ob;
  int tt = (t<CH*CH*27)? t : t-CH*CH*27;
  int frag=tt>>9, l=(tt>>3)&63, j=tt&7;
  int tap=frag>>3, hh=(frag>>2)&1, nf=frag&3;
  int oc=nf*16+(l&15);
  int ci=hh*32+(l>>4)*8+j;
  o[tt]=f2bf(w[oc*1728 + ci*27 + tap]);
}

// ------------- MFMA implicit-GEMM 3x3x3 conv + bias + BN + leaky -------------
// tile 4z x 8y x 8x (256 cells), 4 waves (wave = z-layer, M=64 cells/wave).
// ALL 64 ci staged once: 77 KB DYNAMIC LDS -> 2 blocks/CU. batch = bid&7.
// (R20 conv: single stage -> one barrier -> 27 contiguous taps. T14 reverted.)
#define CONV_TAP(AF, BW) \
  _Pragma("unroll") for(int ks=0;ks<2;ks++) \
    _Pragma("unroll") for(int mf=0;mf<4;mf++) \
      _Pragma("unroll") for(int nf=0;nf<4;nf++) \
        acc[mf][nf]=__builtin_amdgcn_mfma_f32_16x16x32_bf16(AF[ks*4+mf],BW[ks*4+nf],acc[mf][nf],0,0,0);

__global__ __launch_bounds__(256,2) void k_conv_mfma(
    const short* __restrict__ gin, short* __restrict__ gout,
    const short* __restrict__ wt3, const float* __restrict__ bias,
    const float* __restrict__ bg, const float* __restrict__ bb,
    const float* __restrict__ bm, const float* __restrict__ bv){
  extern __shared__ __align__(16) short in_s[];   // 8*SS3*8 shorts = 77056 B
  int tid=threadIdx.x;
  int bid=blockIdx.x;
  int blk=(bid&7)*128 + (bid>>3);     // XCD-chunked bijective swizzle (1024%8==0)
  int b=blk>>7; int rem=blk&127;
  int zt=rem>>4, yt=(rem>>2)&3, xt=rem&3;
  int z0=zt*4, y0=yt*8, x0=xt*8;
  const short* gbase = gin + (size_t)b*R3*CH;

  int lane=tid&63, zl=tid>>6;
  int r15=lane&15, g=lane>>4;
  int ix=r15&7, iy=r15>>3;

  float4_ acc[4][4];
  #pragma unroll
  for(int mf=0;mf<4;mf++)
    #pragma unroll
    for(int nf=0;nf<4;nf++) acc[mf][nf]=(float4_){0.f,0.f,0.f,0.f};

  short8* s8=(short8*)in_s;

  // ---- stage 6z x 10y x 10x halo, ALL 64 ci (8 cb of 8), single pass ----
  for(int it=0; it<19; it++){
    int e=tid+it*256;
    if(e<4800){
      int ss=e>>3, cb=e&7;
      int z=ss/100, r2=ss-z*100, y=r2/10, x=r2-y*10;
      int gz=z0-1+z, gy=y0-1+y, gx=x0-1+x;
      short8 v={0,0,0,0,0,0,0,0};
      if(((unsigned)gz<32u)&&((unsigned)gy<32u)&&((unsigned)gx<32u))
        v=*(const short8*)(gbase + ((gz<<10)+(gy<<5)+gx)*CH + cb*8);
      s8[cb*SS3+ss]=v;
    }
  }
  __syncthreads();

  const short8* wb = ((const short8*)wt3) + lane;
  short8 bw0[8], bw1[8], aA[8], aB[8];
  #pragma unroll
  for(int f=0;f<8;f++) bw0[f]=wb[f*64];
  #pragma unroll
  for(int f=0;f<8;f++) bw1[f]=wb[512+f*64];
  // preload A for tap 0: cell = zl*100 + (mf*2+iy)*10 + ix
  #pragma unroll
  for(int ks=0;ks<2;ks++)
    #pragma unroll
    for(int mf=0;mf<4;mf++)
      aA[ks*4+mf]=s8[(ks*4+g)*SS3 + zl*100 + (mf*2+iy)*10 + ix];

  for(int tt=0; tt<27; tt+=2){
    if(tt+1<27){
      int t1=tt+1, kz=t1/9, r=t1-kz*9, ky=r/3, kx=r-ky*3;
      #pragma unroll
      for(int ks=0;ks<2;ks++)
        #pragma unroll
        for(int mf=0;mf<4;mf++)
          aB[ks*4+mf]=s8[(ks*4+g)*SS3 + (zl+kz)*100 + (mf*2+iy+ky)*10 + ix+kx];
    }
    CONV_TAP(aA, bw0);
    if(tt+2<27){
      #pragma unroll
      for(int f=0;f<8;f++) bw0[f]=wb[(tt+2)*512+f*64];
    }
    if(tt+1<27){
      if(tt+2<27){
        int t2=tt+2, kz=t2/9, r=t2-kz*9, ky=r/3, kx=r-ky*3;
        #pragma unroll
        for(int ks=0;ks<2;ks++)
          #pragma unroll
          for(int mf=0;mf<4;mf++)
            aA[ks*4+mf]=s8[(ks*4+g)*SS3 + (zl+kz)*100 + (mf*2+iy+ky)*10 + ix+kx];
      }
      CONV_TAP(aB, bw1);
      if(tt+3<27){
        #pragma unroll
        for(int f=0;f<8;f++) bw1[f]=wb[(tt+3)*512+f*64];
      }
    }
  }

  // ---- epilogue: bias + BN + leaky -> LDS bf16 repack -> coalesced stores ----
  __syncthreads();
  short* ot=(short*)in_s;             // [256 cells][stride 72] = 36864 B
  #pragma unroll
  for(int nf=0;nf<4;nf++){
    int oc=nf*16+r15;
    float iv=bg[oc]/sqrtf(bv[oc]+BNEPS);
    float sh=bias[oc]*iv + bb[oc]-bm[oc]*iv;
    #pragma unroll
    for(int mf=0;mf<4;mf++){
      #pragma unroll
      for(int q=0;q<4;q++){
        int m=mf*16+g*4+q;            // y=m>>3, x=m&7
        float val=acc[mf][nf][q]*iv+sh;
        val = val>=0.f ? val : LEAK*val;
        ot[(zl*64+m)*72 + oc]=f2bf(val);
      }
    }
  }
  __syncthreads();
  short* go = gout + (size_t)b*R3*CH;
  #pragma unroll
  for(int it=0;it<8;it++){
    int e=tid+it*256;
    int vr=e>>3, j=e&7;
    int zz=vr>>6, rr=vr&63;
    short8 v=*(short8*)(ot + vr*72 + j*8);
    *(short8*)(go + ((size_t)((z0+zz)*1024 + (y0+(rr>>3))*32 + x0+(rr&7)))*CH + j*8)=v;
  }
}

// ------- point MLP + fused GN partial stats; XCD-affinity -------
__global__ __launch_bounds__(256,2) void k_ptgemm(
    const float* __restrict__ feat, const float* __restrict__ w,
    const float* __restrict__ bias, float* __restrict__ y,
    float* __restrict__ stp){
  __shared__ float ws_[64*64];
  __shared__ float ft[64*64];
  __shared__ float sg[8], qg[8];
  int tid=threadIdx.x;
  int bid=blockIdx.x;
  int blk=(bid&7)*64 + (bid>>3);
  int b=blk>>6, n0=(blk&63)*64;
  for(int e=tid;e<4096;e+=256) ws_[e]=w[e];
  for(int e=tid;e<4096;e+=256){
    int c=e>>6, nl=e&63;
    ft[nl*64 + (c ^ ((nl&7)<<2))]=feat[(size_t)(b*CH+c)*NP + n0+nl];
  }
  if(tid<8){ sg[tid]=0.f; qg[tid]=0.f; }
  __syncthreads();
  int nl=tid&63, qq=tid>>6;
  float av[16];
  #pragma unroll
  for(int j=0;j<16;j++) av[j]=bias[qq*16+j];
  for(int c4=0;c4<64;c4+=4){
    float4_ fv=*(float4_*)&ft[nl*64 + (c4 ^ ((nl&7)<<2))];
    #pragma unroll
    for(int j=0;j<16;j++){
      float4_ wv4=*(float4_*)&ws_[(qq*16+j)*64+c4];
      av[j]=fmaf(fv[0],wv4[0],fmaf(fv[1],wv4[1],fmaf(fv[2],wv4[2],fmaf(fv[3],wv4[3],av[j]))));
    }
  }
  float* yp = y + ((size_t)(b*NP+n0+nl))*64 + qq*16;
  #pragma unroll
  for(int q4=0;q4<4;q4++)
    *(float4_*)(yp+q4*4)=(float4_){av[q4*4+0],av[q4*4+1],av[q4*4+2],av[q4*4+3]};
  float ps[2]={0.f,0.f}, pq[2]={0.f,0.f};
  #pragma unroll
  for(int j=0;j<16;j++){
    int gi=j>>3;
    ps[gi]+=av[j]; pq[gi]+=av[j]*av[j];
  }
  #pragma unroll
  for(int off=32;off>0;off>>=1){
    ps[0]+=__shfl_down(ps[0],off,64); pq[0]+=__shfl_down(pq[0],off,64);
    ps[1]+=__shfl_down(ps[1],off,64); pq[1]+=__shfl_down(pq[1],off,64);
  }
  if((tid&63)==0){
    atomicAdd(&sg[qq*2+0],ps[0]); atomicAdd(&qg[qq*2+0],pq[0]);
    atomicAdd(&sg[qq*2+1],ps[1]); atomicAdd(&qg[qq*2+1],pq[1]);
  }
  __syncthreads();
  if(tid<8){
    atomicAdd(&stp[(b*8+tid)*2+0], sg[tid]);
    atomicAdd(&stp[(b*8+tid)*2+1], qg[tid]);
  }
}

// ------- devoxelize + GN finalize + affine + swish + add; XCD-affinity -------
__global__ void k_fuse(const short* __restrict__ grid, const float* __restrict__ nc,
                       const float* __restrict__ py, const float* __restrict__ stp,
                       const float* __restrict__ gg, const float* __restrict__ gb,
                       float* __restrict__ out){
  __shared__ float ot[64][65];
  __shared__ float gmu[8], grs[8];
  int tid=threadIdx.x;
  int bid=blockIdx.x;
  int blk=(bid&7)*64 + (bid>>3);
  int b=blk>>6, n0=(blk&63)*64;
  int nl=tid>>2, qq=tid&3;
  int n=n0+nl;

  if(tid<8){
    float s=stp[(b*8+tid)*2+0], q=stp[(b*8+tid)*2+1];
    float mu=s/(8.f*NP);
    float var=q/(8.f*NP)-mu*mu;
    gmu[tid]=mu;
    grs[tid]=1.0f/sqrtf(var+GNEPS);
  }
  __syncthreads();

  float d_[3]; int i0[3], i1[3];
  #pragma unroll
  for(int dd=0;dd<3;dd++){
    float c=nc[(b*3+dd)*NP+n];
    c=fminf(fmaxf(c,0.f),31.f);
    float f=floorf(c);
    d_[dd]=c-f;
    i0[dd]=(int)f;
    i1[dd]=min(i0[dd]+1,31);
  }
  int idx8[8]; float w8[8];
  #pragma unroll
  for(int k=0;k<8;k++){
    int xx=(k&4)?i1[0]:i0[0];
    int yy=(k&2)?i1[1]:i0[1];
    int zz=(k&1)?i1[2]:i0[2];
    float wx=(k&4)?d_[0]:(1.f-d_[0]);
    float wy=(k&2)?d_[1]:(1.f-d_[1]);
    float wz=(k&1)?d_[2]:(1.f-d_[2]);
    idx8[k]=xx*1024+yy*32+zz;
    w8[k]=wx*wy*wz;
  }
  const short* gbase = grid + (size_t)b*R3*CH;
  const float* pp = py + ((size_t)(b*NP+n))*64;
  #pragma unroll
  for(int c8=0;c8<2;c8++){
    int c0=qq*16+c8*8;
    float dv[8]={0.f,0.f,0.f,0.f,0.f,0.f,0.f,0.f};
    #pragma unroll
    for(int k=0;k<8;k++){
      short8 gv=*(const short8*)(gbase + (size_t)idx8[k]*CH + c0);
      #pragma unroll
      for(int j=0;j<8;j++) dv[j]+=w8[k]*bf2f(gv[j]);
    }
    float4_ p0=*(const float4_*)(pp+c0);
    float4_ p1=*(const float4_*)(pp+c0+4);
    #pragma unroll
    for(int j=0;j<8;j++){
      int c=c0+j;
      float pv = j<4 ? p0[j] : p1[j-4];
      float yn=(pv-gmu[c>>3])*grs[c>>3]*gg[c]+gb[c];
      float sw=yn/(1.f+expf(-yn));
      ot[c][nl]=dv[j]+sw;
    }
  }
  __syncthreads();
  for(int i=tid;i<1024;i+=256){
    int c=i>>4, sg=i&15;
    float4_ v={ot[c][sg*4+0],ot[c][sg*4+1],ot[c][sg*4+2],ot[c][sg*4+3]};
    *(float4_*)(out + (size_t)(b*CH+c)*NP + n0 + sg*4) = v;
  }
}

// ---------------- merged passthrough copy (coords + temb) ----------------
__global__ void k_copyall(const float* __restrict__ coords, const float* __restrict__ temb,
                          float* __restrict__ out){
  int t=blockIdx.x*256+threadIdx.x;
  if(t<98304) out[2097152+t]=coords[t];
  else if(t<98816) out[2195456+(t-98304)]=temb[t-98304];
}

extern "C" void kernel_launch(void* const* d_in, const int* in_sizes, int n_in,
                              void* d_out, int out_size, void* d_ws, size_t ws_size,
                              hipStream_t stream){
  const float* features=(const float*)d_in[0];
  const float* coords  =(const float*)d_in[1];
  const float* temb    =(const float*)d_in[2];
  const float* c1w=(const float*)d_in[3];
  const float* c1b=(const float*)d_in[4];
  const float* b1g=(const float*)d_in[5];
  const float* b1b=(const float*)d_in[6];
  const float* b1m=(const float*)d_in[7];
  const float* b1v=(const float*)d_in[8];
  const float* c2w=(const float*)d_in[9];
  const float* c2b=(const float*)d_in[10];
  const float* b2g=(const float*)d_in[11];
  const float* b2b=(const float*)d_in[12];
  const float* b2m=(const float*)d_in[13];
  const float* b2v=(const float*)d_in[14];
  const float* pfw=(const float*)d_in[15];
  const float* pfb=(const float*)d_in[16];
  const float* gng=(const float*)d_in[17];
  const float* gnb=(const float*)d_in[18];

  float* F=(float*)d_ws;
  float* ms  = F + 0;                   // 32
  float* nc  = F + 32;                  // 98304
  int*   vi  = (int*)(F + 98336);       // 32768
  short* w1t = (short*)(F + 131104);    // 110592 sh = 55296 f
  short* w2t = (short*)(F + 186400);    // 55296 f
  float* py  = F + 241696;              // 2097152  ([b][n][64] layout)
  float* stp = F + 2338848;             // 128  (memset start)
  float* cnt = F + 2338976;             // 262144
  float* gA  = F + 2601120;             // 16777216 (zeroed sparsely by k_assignzero)
  short* gBF1= (short*)(F + 19378336);  // 16777216 sh = 8388608 f
  short* gBF2= (short*)(F + 27766944);  // 8388608 f
  float* out=(float*)d_out;

  static bool attr_set=false;
  if(!attr_set){
    hipFuncSetAttribute((const void*)k_conv_mfma,
                        hipFuncAttributeMaxDynamicSharedMemorySize, 77056);
    attr_set=true;
  }

  hipMemsetAsync(stp, 0, (size_t)(128+262144)*4, stream);   // stp + cnt only

  k_voxstats <<<8,256,0,stream>>>(coords, ms);
  k_assignzero<<<8192,256,0,stream>>>(coords, ms, nc, vi, gA);
  k_scatter  <<<512,256,0,stream>>>(features, vi, gA, cnt);
  k_gridmean <<<8192,256,0,stream>>>(gA, cnt, gBF1);
  k_wt3x2    <<<864,256,0,stream>>>(c1w, c2w, w1t, w2t);
  k_conv_mfma<<<1024,256,77056,stream>>>(gBF1, gBF2, w1t, c1b, b1g, b1b, b1m, b1v);
  k_conv_mfma<<<1024,256,77056,stream>>>(gBF2, gBF1, w2t, c2b, b2g, b2b, b2m, b2v);
  k_ptgemm   <<<512,256,0,stream>>>(features, pfw, pfb, py, stp);
  k_fuse     <<<512,256,0,stream>>>(gBF1, nc, py, stp, gng, gnb, out);
  k_copyall  <<<386,256,0,stream>>>(coords, temb, out);
}